// Round 7
// baseline (554.147 us; speedup 1.0000x reference)
//
#include <hip/hip_runtime.h>

// FDTD 2-step update, float32.
// Fields: E (B,1024,1024), Hx (B,1022,1023), Hy (B,1023,1022), B=8.
// v6: 4 launches (v2 structure = best so far), register-streaming y-march:
//   block = (batch b, 8-row strip), 256 threads x 4 cols = full 1024-col row.
//   Stencil window held in registers; one new row-load per step; all
//   column-stencil terms come from the register window. Slot indices are
//   compile-time ((i+d)&7) because strips are 8-aligned and loops unrolled.
//   Edge columns (tid 0/255) use the verified scalar global-load path.

#define KF0 (-11.0f / 12.0f)
#define KF1 (1.5f)
#define KF2 (-0.75f)
#define KF3 (1.0f / 6.0f)
#define KB0 (-1.0f / 6.0f)
#define KB1 (0.75f)
#define KB2 (-1.5f)
#define KB3 (11.0f / 12.0f)

typedef float f4 __attribute__((ext_vector_type(4)));

__device__ __forceinline__ f4 ld4(const float* p) { f4 v; __builtin_memcpy(&v, p, 16); return v; }
__device__ __forceinline__ void st4(float* p, f4 v) { __builtin_memcpy(p, &v, 16); }

// ---- scalar reference paths (verified v2), global loads, for edge columns ----

__device__ __forceinline__ float amper_pt(const float* __restrict__ e,
                                          const float* __restrict__ hx,
                                          const float* __restrict__ hy,
                                          int y, int x)
{
    float v = e[y * 1024 + x];
    if ((y >= 2) & (y < 1022) & (x >= 2) & (x < 1022)) {
        const float* r0 = hy + (y - 2) * 1022 + (x - 2);
        const float* r1 = r0 + 1022;
        const float* r2 = r1 + 1022;
        v += 0.5f * ((r0[0] + r0[2])
                     - (r1[0] + r1[1] + r1[2])
                     + (r2[0] + r2[1] + r2[2]));
        const float* q0 = hx + (y - 2) * 1023 + (x - 2);
        const float* q1 = q0 + 1023;
        const float* q2 = q1 + 1023;
        v -= 0.5f * ((q0[0] - q0[1] + q0[2])
                     + (-q1[1] + q1[2])
                     + (q2[0] - q2[1] + q2[2]));
    }
    bool cx = (x >= 1) & (x < 1023);
    if ((y < 1020) & cx) {
        const float* c = hy + y * 1022 + (x - 1);
        v += KF0 * c[0] + KF1 * c[1022] + KF2 * c[2044] + KF3 * c[3066];
    }
    if ((y >= 4) & cx) {
        const float* c = hy + (y - 4) * 1022 + (x - 1);
        v += KB0 * c[0] + KB1 * c[1022] + KB2 * c[2044] + KB3 * c[3066];
    }
    bool cy = (y >= 1) & (y < 1023);
    if (cy & (x < 1020)) {
        const float* r = hx + (y - 1) * 1023 + x;
        v -= KF0 * r[0] + KF1 * r[1] + KF2 * r[2] + KF3 * r[3];
    }
    if (cy & (x >= 4)) {
        const float* r = hx + (y - 1) * 1023 + (x - 4);
        v -= KB0 * r[0] + KB1 * r[1] + KB2 * r[2] + KB3 * r[3];
    }
    return v;
}

__device__ __forceinline__ float far_hx_pt(const float* __restrict__ e,
                                           const float* __restrict__ hxp,
                                           int y, int x)
{
    float v = hxp[y * 1023 + x];
    if ((x >= 1) & (x < 1022)) {
        const float* r0 = e + y * 1024 + (x - 1);
        const float* r1 = r0 + 1024;
        const float* r2 = r1 + 1024;
        v -= 0.5f * ((r0[0] - r0[1] + r0[2])
                     + (-r1[1] + r1[2])
                     + (r2[0] - r2[1] + r2[2]));
    }
    if (x < 1021) {
        const float* r = e + (y + 1) * 1024 + x;
        v -= KF0 * r[0] + KF1 * r[1] + KF2 * r[2] + KF3 * r[3];
    }
    if (x >= 2) {
        const float* r = e + (y + 1) * 1024 + (x - 2);
        v -= KB0 * r[0] + KB1 * r[1] + KB2 * r[2] + KB3 * r[3];
    }
    return v;
}

__device__ __forceinline__ float far_hy_pt(const float* __restrict__ e,
                                           const float* __restrict__ hyp,
                                           int y, int x)
{
    float v = hyp[y * 1022 + x];
    if ((y >= 1) & (y < 1022)) {
        const float* r0 = e + (y - 1) * 1024 + x;
        const float* r1 = r0 + 1024;
        const float* r2 = r1 + 1024;
        v += 0.5f * ((r0[0] + r0[2])
                     - (r1[0] + r1[1] + r1[2])
                     + (r2[0] + r2[1] + r2[2]));
    }
    if (y < 1021) {
        const float* c = e + y * 1024 + (x + 1);
        v += KF0 * c[0] + KF1 * c[1024] + KF2 * c[2048] + KF3 * c[3072];
    }
    if (y >= 2) {
        const float* c = e + (y - 2) * 1024 + (x + 1);
        v += KB0 * c[0] + KB1 * c[1024] + KB2 * c[2048] + KB3 * c[3072];
    }
    return v;
}

// ---------------- amper march: E_n over (1024,1024) ----------------
// Window: W[8][6]  = Hy rows y-4..y+3, cols x0-2..x0+3  (slot (t+8)&7)
//         X[4][12] = Hx rows y-2..y,   cols x0-4..x0+7  (slot (t+8)&3)

__global__ __launch_bounds__(256) void amper_m(
    const float* __restrict__ E, int sEb,
    const float* __restrict__ Hx, int sHxb,
    const float* __restrict__ Hy, int sHyb,
    float* __restrict__ Eo, int sEob)
{
    int b  = blockIdx.x;           // 0..7
    int y0 = blockIdx.y << 3;      // 8-aligned strip start
    int tid = threadIdx.x;
    int x0 = tid << 2;

    const float* e  = E  + (size_t)b * sEb;
    const float* hx = Hx + (size_t)b * sHxb;
    const float* hy = Hy + (size_t)b * sHyb;
    float* eo = Eo + (size_t)b * sEob;

    bool fast = (x0 >= 4) & (x0 <= 1016);

    if (fast) {
        float W[8][6];
        float X[4][12];

        // prologue: Hy rows y0-4..y0+2
        #pragma unroll
        for (int t = -4; t <= 2; ++t) {
            int gr = y0 + t;
            float* w = W[(t + 8) & 7];
            if ((unsigned)gr < 1023u) {
                __builtin_memcpy(w, hy + gr * 1022 + (x0 - 2), 24);
            } else {
                #pragma unroll
                for (int k = 0; k < 6; ++k) w[k] = 0.f;
            }
        }
        // prologue: Hx rows y0-2, y0-1
        #pragma unroll
        for (int t = -2; t <= -1; ++t) {
            int gr = y0 + t;
            float* w = X[(t + 8) & 3];
            if ((unsigned)gr < 1022u) {
                __builtin_memcpy(w, hx + gr * 1023 + (x0 - 4), 48);
            } else {
                #pragma unroll
                for (int k = 0; k < 12; ++k) w[k] = 0.f;
            }
        }

        #define WY(d) (W[(i + (d) + 8) & 7])
        #define XX(d) (X[(i + (d) + 8) & 3])

        #pragma unroll
        for (int i = 0; i < 8; ++i) {
            int y = y0 + i;
            // load Hy row y+3
            {
                int gr = y + 3;
                float* w = W[(i + 3) & 7];
                if (gr <= 1022) {
                    __builtin_memcpy(w, hy + gr * 1022 + (x0 - 2), 24);
                } else {
                    #pragma unroll
                    for (int k = 0; k < 6; ++k) w[k] = 0.f;
                }
            }
            // load Hx row y
            {
                float* w = X[(i + 8) & 3];
                if (y <= 1021) {
                    __builtin_memcpy(w, hx + y * 1023 + (x0 - 4), 48);
                } else {
                    #pragma unroll
                    for (int k = 0; k < 12; ++k) w[k] = 0.f;
                }
            }
            f4 ev = ld4(e + y * 1024 + x0);
            f4 o;
            bool gin = (y >= 2) & (y < 1022);
            bool gf  = (y < 1020);
            bool gb  = (y >= 4);
            bool gc  = (y >= 1) & (y < 1023);
            #pragma unroll
            for (int j = 0; j < 4; ++j) {
                float v = ev[j];
                if (gin) {
                    v += 0.5f * ((WY(-2)[j] + WY(-2)[j + 2])
                                 - (WY(-1)[j] + WY(-1)[j + 1] + WY(-1)[j + 2])
                                 + (WY(0)[j] + WY(0)[j + 1] + WY(0)[j + 2]));
                    v -= 0.5f * ((XX(-2)[j + 2] - XX(-2)[j + 3] + XX(-2)[j + 4])
                                 + (-XX(-1)[j + 3] + XX(-1)[j + 4])
                                 + (XX(0)[j + 2] - XX(0)[j + 3] + XX(0)[j + 4]));
                }
                if (gf)
                    v += KF0 * WY(0)[j + 1] + KF1 * WY(1)[j + 1]
                       + KF2 * WY(2)[j + 1] + KF3 * WY(3)[j + 1];
                if (gb)
                    v += KB0 * WY(-4)[j + 1] + KB1 * WY(-3)[j + 1]
                       + KB2 * WY(-2)[j + 1] + KB3 * WY(-1)[j + 1];
                if (gc) {
                    v -= KF0 * XX(-1)[j + 4] + KF1 * XX(-1)[j + 5]
                       + KF2 * XX(-1)[j + 6] + KF3 * XX(-1)[j + 7];
                    v -= KB0 * XX(-1)[j] + KB1 * XX(-1)[j + 1]
                       + KB2 * XX(-1)[j + 2] + KB3 * XX(-1)[j + 3];
                }
                o[j] = v;
            }
            st4(eo + y * 1024 + x0, o);
        }
        #undef WY
        #undef XX
    } else {
        for (int i = 0; i < 8; ++i) {
            int y = y0 + i;
            #pragma unroll
            for (int k = 0; k < 4; ++k)
                eo[y * 1024 + x0 + k] = amper_pt(e, hx, hy, y, x0 + k);
        }
    }
}

// ---------------- faraday march: Hx_n (1022,1023), Hy_n (1023,1022) ----------
// Window: Ew[8][12] = E rows y-2..y+3, cols x0-4..x0+7 (slot (t+8)&7)

__global__ __launch_bounds__(256) void faraday_m(
    const float* __restrict__ E, int sEb,
    const float* __restrict__ Hx, int sHxb,
    const float* __restrict__ Hy, int sHyb,
    float* __restrict__ Hxo, int sHxob,
    float* __restrict__ Hyo, int sHyob)
{
    int b  = blockIdx.x;           // 0..7
    int y0 = blockIdx.y << 3;
    int tid = threadIdx.x;
    int x0 = tid << 2;

    const float* e   = E  + (size_t)b * sEb;
    const float* hxp = Hx + (size_t)b * sHxb;
    const float* hyp = Hy + (size_t)b * sHyb;
    float* hxo = Hxo + (size_t)b * sHxob;
    float* hyo = Hyo + (size_t)b * sHyob;

    bool fast = (x0 >= 4) & (x0 <= 1016);

    if (fast) {
        float Ew[8][12];

        // prologue: E rows y0-2..y0+2
        #pragma unroll
        for (int t = -2; t <= 2; ++t) {
            int gr = y0 + t;
            float* w = Ew[(t + 8) & 7];
            if ((unsigned)gr < 1024u) {
                __builtin_memcpy(w, e + gr * 1024 + (x0 - 4), 48);
            } else {
                #pragma unroll
                for (int k = 0; k < 12; ++k) w[k] = 0.f;
            }
        }

        #define EWD(d) (Ew[(i + (d) + 8) & 7])

        #pragma unroll
        for (int i = 0; i < 8; ++i) {
            int y = y0 + i;
            // load E row y+3
            {
                int gr = y + 3;
                float* w = Ew[(i + 3) & 7];
                if (gr <= 1023) {
                    __builtin_memcpy(w, e + gr * 1024 + (x0 - 4), 48);
                } else {
                    #pragma unroll
                    for (int k = 0; k < 12; ++k) w[k] = 0.f;
                }
            }

            // Hx part: rows 0..1021
            if (y < 1022) {
                f4 hv = ld4(hxp + y * 1023 + x0);
                f4 o;
                #pragma unroll
                for (int j = 0; j < 4; ++j) {
                    float v = hv[j];
                    v -= 0.5f * ((EWD(0)[j + 3] - EWD(0)[j + 4] + EWD(0)[j + 5])
                                 + (-EWD(1)[j + 4] + EWD(1)[j + 5])
                                 + (EWD(2)[j + 3] - EWD(2)[j + 4] + EWD(2)[j + 5]));
                    v -= KF0 * EWD(1)[j + 4] + KF1 * EWD(1)[j + 5]
                       + KF2 * EWD(1)[j + 6] + KF3 * EWD(1)[j + 7];
                    v -= KB0 * EWD(1)[j + 2] + KB1 * EWD(1)[j + 3]
                       + KB2 * EWD(1)[j + 4] + KB3 * EWD(1)[j + 5];
                    o[j] = v;
                }
                st4(hxo + y * 1023 + x0, o);
            }

            // Hy part: rows 0..1022
            if (y < 1023) {
                f4 hv = ld4(hyp + y * 1022 + x0);
                f4 o;
                bool ga = (y >= 1) & (y < 1022);
                bool gf = (y < 1021);
                bool gb = (y >= 2);
                #pragma unroll
                for (int j = 0; j < 4; ++j) {
                    float v = hv[j];
                    if (ga)
                        v += 0.5f * ((EWD(-1)[j + 4] + EWD(-1)[j + 6])
                                     - (EWD(0)[j + 4] + EWD(0)[j + 5] + EWD(0)[j + 6])
                                     + (EWD(1)[j + 4] + EWD(1)[j + 5] + EWD(1)[j + 6]));
                    if (gf)
                        v += KF0 * EWD(0)[j + 5] + KF1 * EWD(1)[j + 5]
                           + KF2 * EWD(2)[j + 5] + KF3 * EWD(3)[j + 5];
                    if (gb)
                        v += KB0 * EWD(-2)[j + 5] + KB1 * EWD(-1)[j + 5]
                           + KB2 * EWD(0)[j + 5] + KB3 * EWD(1)[j + 5];
                    o[j] = v;
                }
                st4(hyo + y * 1022 + x0, o);
            }
        }
        #undef EWD
    } else {
        for (int i = 0; i < 8; ++i) {
            int y = y0 + i;
            if (y < 1022) {
                #pragma unroll
                for (int k = 0; k < 4; ++k) {
                    int x = x0 + k;
                    if (x < 1023) hxo[y * 1023 + x] = far_hx_pt(e, hxp, y, x);
                }
            }
            if (y < 1023) {
                #pragma unroll
                for (int k = 0; k < 4; ++k) {
                    int x = x0 + k;
                    if (x < 1022) hyo[y * 1022 + x] = far_hy_pt(e, hyp, y, x);
                }
            }
        }
    }
}

extern "C" void kernel_launch(void* const* d_in, const int* in_sizes, int n_in,
                              void* d_out, int out_size, void* d_ws, size_t ws_size,
                              hipStream_t stream)
{
    const float* E  = (const float*)d_in[0];
    const float* Hx = (const float*)d_in[1];
    const float* Hy = (const float*)d_in[2];

    float* out = (float*)d_out;
    float* Eo  = out;                      // 8 * 2048 * 1024
    float* Hxo = out + 16777216;           // 8 * 2044 * 1023
    float* Hyo = Hxo + 16728096;           // 8 * 2046 * 1022

    const int sE  = 1024 * 1024;
    const int sHx = 1022 * 1023;
    const int sHy = 1023 * 1022;
    const int sEo = 2 * 1024 * 1024;
    const int sHo = 2 * 1045506;

    dim3 blk(256, 1, 1);
    dim3 g(8, 128, 1);   // (batch, 8-row strip)

    // step 1: E_n = amper(E, Hx, Hy)
    amper_m<<<g, blk, 0, stream>>>(E, sE, Hx, sHx, Hy, sHy, Eo, sEo);
    // step 2: Hx_n, Hy_n = faraday(E_n, Hx, Hy)
    faraday_m<<<g, blk, 0, stream>>>(Eo, sEo, Hx, sHx, Hy, sHy,
                                     Hxo, sHo, Hyo, sHo);
    // step 3: E_m = amper(E_n, Hx_n, Hy_n)
    amper_m<<<g, blk, 0, stream>>>(Eo, sEo, Hxo, sHo, Hyo, sHo,
                                   Eo + 1024 * 1024, sEo);
    // step 4: Hx_m, Hy_m = faraday(E_m, Hx_n, Hy_n)
    faraday_m<<<g, blk, 0, stream>>>(Eo + 1024 * 1024, sEo, Hxo, sHo, Hyo, sHo,
                                     Hxo + 1045506, sHo, Hyo + 1045506, sHo);
}